// Round 1
// baseline (265.181 us; speedup 1.0000x reference)
//
#include <hip/hip_runtime.h>

// VoxelProjection_fish: gather fisheye features per voxel, weight, write BEV grid.
// out[((z*C + c)*BEV_H + h)*BEV_W + w] = input[c*HF*WF + vv[l]*WF + uu[l]] * valid[l]*density[l]
//   where l = (z*BEV_H + h)*BEV_W + w.

#define C_IN  336
#define ZB    6
#define BEV_H 240
#define BEV_W 120
#define LVOX  (ZB * BEV_H * BEV_W)   // 172800
#define HF    160
#define WF    256
#define PIX   (HF * WF)              // 40960
#define HW    (BEV_H * BEV_W)        // 28800 (divisible by 64 -> z wave-uniform)
#define CPT   16                     // channels per thread
#define NCHUNK (C_IN / CPT)          // 21

__global__ __launch_bounds__(256) void voxel_proj_kernel(
    const float* __restrict__ input,
    const int*   __restrict__ uu,
    const int*   __restrict__ vv,
    const float* __restrict__ valid,
    const float* __restrict__ density,
    float*       __restrict__ out)
{
    const int l = blockIdx.x * 256 + threadIdx.x;   // voxel index, exact: 675*256 = 172800
    const int p = vv[l] * WF + uu[l];               // flat pixel index
    const float w = valid[l] * density[l];

    const int z  = l / HW;                          // wave-uniform
    const int hw = l - z * HW;                      // contiguous across lanes

    const float* inb  = input + p;
    float*       outb = out + (size_t)z * C_IN * HW + hw;

    const int c0 = blockIdx.y * CPT;
    #pragma unroll
    for (int i = 0; i < CPT; ++i) {
        const int c = c0 + i;
        outb[(size_t)c * HW] = inb[(size_t)c * PIX] * w;   // coalesced store, scattered (cached) load
    }
}

extern "C" void kernel_launch(void* const* d_in, const int* in_sizes, int n_in,
                              void* d_out, int out_size, void* d_ws, size_t ws_size,
                              hipStream_t stream)
{
    const float* input   = (const float*)d_in[0];
    const int*   uu      = (const int*)  d_in[1];
    const int*   vv      = (const int*)  d_in[2];
    const float* valid   = (const float*)d_in[3];
    const float* density = (const float*)d_in[4];
    float*       out     = (float*)d_out;

    dim3 grid(LVOX / 256, NCHUNK);   // (675, 21)
    voxel_proj_kernel<<<grid, dim3(256), 0, stream>>>(input, uu, vv, valid, density, out);
}

// Round 2
// 106.794 us; speedup vs baseline: 2.4831x; 2.4831x over previous
//
#include <hip/hip_runtime.h>

// VoxelProjection_fish — two-phase: (A) transpose input to pixel-major,
// (B) contiguous per-voxel gather + LDS transpose + coalesced BEV store.

#define C_IN  336
#define ZB    6
#define BEV_H 240
#define BEV_W 120
#define LVOX  (ZB * BEV_H * BEV_W)   // 172800
#define HF    160
#define WF    256
#define PIX   (HF * WF)              // 40960
#define HW    (BEV_H * BEV_W)        // 28800

// ---------- Kernel A: transpose input [C_IN][PIX] -> T [PIX][C_IN] ----------
#define TA_P 64
#define TA_C 48   // 336 = 7 * 48
__global__ __launch_bounds__(256) void transpose_kernel(
    const float* __restrict__ in, float* __restrict__ T)
{
    __shared__ float tile[TA_C][TA_P + 1];
    const int p0 = blockIdx.x * TA_P;
    const int c0 = blockIdx.y * TA_C;
    const int t  = threadIdx.x;

    #pragma unroll
    for (int i = 0; i < (TA_P * TA_C) / 256; ++i) {   // 12
        int idx = i * 256 + t;
        int cl = idx >> 6;          // /64 : 4 channel rows per iter
        int pl = idx & 63;
        tile[cl][pl] = in[(size_t)(c0 + cl) * PIX + p0 + pl];   // coalesced 256B rows
    }
    __syncthreads();
    #pragma unroll
    for (int i = 0; i < (TA_P * TA_C) / 256; ++i) {   // 12
        int idx = i * 256 + t;
        int cl = idx % TA_C;
        int pl = idx / TA_C;
        T[(size_t)(p0 + pl) * C_IN + c0 + cl] = tile[cl][pl];   // coalesced 192B chunks
    }
}

// ---------- Kernel B: gather rows of T, weight, transpose via LDS, store ----------
#define VB  64                 // voxels per block (64 | 28800 -> z uniform per block)
#define CC  112                // channels per chunk (336 = 3 * 112)
#define NCH (C_IN / CC)        // 3
#define LROW (VB + 1)          // 65 floats, stride-65 reads conflict-free

__global__ __launch_bounds__(256) void gather_kernel(
    const float* __restrict__ T,
    const int*   __restrict__ uu,
    const int*   __restrict__ vv,
    const float* __restrict__ valid,
    const float* __restrict__ density,
    float*       __restrict__ out)
{
    __shared__ float tile[CC * LROW];   // [c_local][voxel], 29.1 KB
    __shared__ int   p_s[VB];
    __shared__ float w_s[VB];

    const int t   = threadIdx.x;
    const int l0  = blockIdx.x * VB;
    const int z   = l0 / HW;            // wave-uniform (450 blocks per z-slab)
    const int hw0 = l0 - z * HW;

    if (t < VB) {
        int l = l0 + t;
        p_s[t] = vv[l] * WF + uu[l];
        w_s[t] = valid[l] * density[l];
    }
    __syncthreads();

    for (int ch = 0; ch < NCH; ++ch) {
        const int c0 = ch * CC;

        // Phase 2: load 64 rows x 28 float4 (contiguous, 64B-aligned: 1344=21*64, 448%64==0)
        #pragma unroll
        for (int i = 0; i < (VB * CC / 4) / 256; ++i) {   // 7
            int idx = i * 256 + t;
            int v = idx / (CC / 4);     // /28 (magic-mul)
            int f = idx - v * (CC / 4);
            const float4 val = *reinterpret_cast<const float4*>(
                &T[(size_t)p_s[v] * C_IN + c0 + f * 4]);
            float w = w_s[v];
            int base = (f * 4) * LROW + v;
            tile[base]          = val.x * w;
            tile[base + LROW]   = val.y * w;
            tile[base + 2*LROW] = val.z * w;
            tile[base + 3*LROW] = val.w * w;
        }
        __syncthreads();

        // Phase 3: per channel-row, 16 lanes x float4 = 256B coalesced stores
        {
            const int vq = (t & 15) * 4;          // voxel quad base
            const int cb = t >> 4;                // 0..15
            #pragma unroll
            for (int i = 0; i < CC / 16; ++i) {   // 7
                int cl = i * 16 + cb;
                float4 o;
                o.x = tile[cl * LROW + vq + 0];   // stride-65 rows: <=2-way, free
                o.y = tile[cl * LROW + vq + 1];
                o.z = tile[cl * LROW + vq + 2];
                o.w = tile[cl * LROW + vq + 3];
                *reinterpret_cast<float4*>(
                    &out[(size_t)(z * C_IN + c0 + cl) * HW + hw0 + vq]) = o;
            }
        }
        __syncthreads();
    }
}

// ---------- Fallback: direct scattered gather (round-1 kernel) ----------
#define CPT 16
__global__ __launch_bounds__(256) void voxel_proj_direct(
    const float* __restrict__ input,
    const int*   __restrict__ uu,
    const int*   __restrict__ vv,
    const float* __restrict__ valid,
    const float* __restrict__ density,
    float*       __restrict__ out)
{
    const int l = blockIdx.x * 256 + threadIdx.x;
    const int p = vv[l] * WF + uu[l];
    const float w = valid[l] * density[l];
    const int z  = l / HW;
    const int hw = l - z * HW;
    const float* inb  = input + p;
    float*       outb = out + (size_t)z * C_IN * HW + hw;
    const int c0 = blockIdx.y * CPT;
    #pragma unroll
    for (int i = 0; i < CPT; ++i) {
        const int c = c0 + i;
        outb[(size_t)c * HW] = inb[(size_t)c * PIX] * w;
    }
}

extern "C" void kernel_launch(void* const* d_in, const int* in_sizes, int n_in,
                              void* d_out, int out_size, void* d_ws, size_t ws_size,
                              hipStream_t stream)
{
    const float* input   = (const float*)d_in[0];
    const int*   uu      = (const int*)  d_in[1];
    const int*   vv      = (const int*)  d_in[2];
    const float* valid   = (const float*)d_in[3];
    const float* density = (const float*)d_in[4];
    float*       out     = (float*)d_out;

    const size_t T_bytes = (size_t)PIX * C_IN * sizeof(float);   // 52.5 MB
    if (ws_size >= T_bytes) {
        float* T = (float*)d_ws;
        transpose_kernel<<<dim3(PIX / TA_P, C_IN / TA_C), dim3(256), 0, stream>>>(input, T);
        gather_kernel<<<dim3(LVOX / VB), dim3(256), 0, stream>>>(T, uu, vv, valid, density, out);
    } else {
        voxel_proj_direct<<<dim3(LVOX / 256, C_IN / CPT), dim3(256), 0, stream>>>(
            input, uu, vv, valid, density, out);
    }
}

// Round 3
// 92.239 us; speedup vs baseline: 2.8749x; 1.1578x over previous
//
#include <hip/hip_runtime.h>
#include <hip/hip_fp16.h>

// VoxelProjection_fish — two-phase: (A) transpose input to pixel-major fp16,
// (B) contiguous per-voxel gather + LDS transpose + coalesced BEV store.

#define C_IN  336
#define ZB    6
#define BEV_H 240
#define BEV_W 120
#define LVOX  (ZB * BEV_H * BEV_W)   // 172800
#define HF    160
#define WF    256
#define PIX   (HF * WF)              // 40960
#define HW    (BEV_H * BEV_W)        // 28800

// ---------- Kernel A: transpose input [C_IN][PIX] f32 -> T2 [PIX][C_IN] f16 ----------
#define TA_P 64
#define TA_C 48   // 336 = 7 * 48
__global__ __launch_bounds__(256) void transpose_f16_kernel(
    const float* __restrict__ in, __half* __restrict__ T2)
{
    __shared__ float tile[TA_C][TA_P + 1];
    const int p0 = blockIdx.x * TA_P;
    const int c0 = blockIdx.y * TA_C;
    const int t  = threadIdx.x;

    #pragma unroll
    for (int i = 0; i < (TA_P * TA_C) / 256; ++i) {   // 12
        int idx = i * 256 + t;
        int cl = idx >> 6;          // 4 channel rows per iter
        int pl = idx & 63;
        tile[cl][pl] = in[(size_t)(c0 + cl) * PIX + p0 + pl];   // coalesced 256B rows
    }
    __syncthreads();
    #pragma unroll
    for (int i = 0; i < (TA_P * TA_C / 2) / 256; ++i) {   // 6: one half2 per thread
        int idx = i * 256 + t;
        int cl2 = idx % (TA_C / 2);     // 0..23 channel-pair
        int pl  = idx / (TA_C / 2);
        __half2 hv = __floats2half2_rn(tile[2 * cl2][pl], tile[2 * cl2 + 1][pl]);
        *reinterpret_cast<__half2*>(
            &T2[(size_t)(p0 + pl) * C_IN + c0 + 2 * cl2]) = hv;   // 96B runs, 4B-aligned
    }
}

// ---------- Kernel B: gather fp16 rows of T2, weight, transpose via LDS, store ----------
#define VB   64                // voxels per block (64 | 28800 -> z uniform)
#define CC   112               // channels per chunk (336 = 3 * 112)
#define NCH  (C_IN / CC)       // 3
#define LROW (VB + 1)          // 65 floats, stride-65 reads conflict-free

__global__ __launch_bounds__(256) void gather_f16_kernel(
    const __half* __restrict__ T2,
    const int*    __restrict__ uu,
    const int*    __restrict__ vv,
    const float*  __restrict__ valid,
    const float*  __restrict__ density,
    float*        __restrict__ out)
{
    __shared__ float tile[CC * LROW];   // [c_local][voxel], 29.1 KB
    __shared__ int   p_s[VB];
    __shared__ float w_s[VB];

    const int t   = threadIdx.x;
    const int l0  = blockIdx.x * VB;
    const int z   = l0 / HW;            // wave-uniform (450 blocks per z-slab)
    const int hw0 = l0 - z * HW;

    if (t < VB) {
        int l = l0 + t;
        p_s[t] = vv[l] * WF + uu[l];
        w_s[t] = valid[l] * density[l];
    }
    __syncthreads();

    for (int ch = 0; ch < NCH; ++ch) {
        const int c0 = ch * CC;

        // Phase 2: 64 rows x 28 uint2-granules (4 half channels, 8B-aligned:
        // row base 672B = 84*8, chunk offsets 224/448B)
        #pragma unroll
        for (int i = 0; i < (VB * CC / 4) / 256; ++i) {   // 7
            int idx = i * 256 + t;
            int v = idx / (CC / 4);     // /28
            int g = idx - v * (CC / 4);
            const uint2 raw = *reinterpret_cast<const uint2*>(
                &T2[(size_t)p_s[v] * C_IN + c0 + g * 4]);
            const __half2 h01 = *reinterpret_cast<const __half2*>(&raw.x);
            const __half2 h23 = *reinterpret_cast<const __half2*>(&raw.y);
            const float2 f01 = __half22float2(h01);
            const float2 f23 = __half22float2(h23);
            const float w = w_s[v];
            int base = (g * 4) * LROW + v;
            tile[base]          = f01.x * w;
            tile[base + LROW]   = f01.y * w;
            tile[base + 2*LROW] = f23.x * w;
            tile[base + 3*LROW] = f23.y * w;
        }
        __syncthreads();

        // Phase 3: per channel-row, 16 lanes x float4 = 256B coalesced stores
        {
            const int vq = (t & 15) * 4;          // voxel quad base
            const int cb = t >> 4;                // 0..15
            #pragma unroll
            for (int i = 0; i < CC / 16; ++i) {   // 7
                int cl = i * 16 + cb;
                float4 o;
                o.x = tile[cl * LROW + vq + 0];   // stride-65 rows: <=2-way, free
                o.y = tile[cl * LROW + vq + 1];
                o.z = tile[cl * LROW + vq + 2];
                o.w = tile[cl * LROW + vq + 3];
                *reinterpret_cast<float4*>(
                    &out[(size_t)(z * C_IN + c0 + cl) * HW + hw0 + vq]) = o;
            }
        }
        __syncthreads();
    }
}

// ---------- Fallback: direct scattered gather (round-1 kernel) ----------
#define CPT 16
__global__ __launch_bounds__(256) void voxel_proj_direct(
    const float* __restrict__ input,
    const int*   __restrict__ uu,
    const int*   __restrict__ vv,
    const float* __restrict__ valid,
    const float* __restrict__ density,
    float*       __restrict__ out)
{
    const int l = blockIdx.x * 256 + threadIdx.x;
    const int p = vv[l] * WF + uu[l];
    const float w = valid[l] * density[l];
    const int z  = l / HW;
    const int hw = l - z * HW;
    const float* inb  = input + p;
    float*       outb = out + (size_t)z * C_IN * HW + hw;
    const int c0 = blockIdx.y * CPT;
    #pragma unroll
    for (int i = 0; i < CPT; ++i) {
        const int c = c0 + i;
        outb[(size_t)c * HW] = inb[(size_t)c * PIX] * w;
    }
}

extern "C" void kernel_launch(void* const* d_in, const int* in_sizes, int n_in,
                              void* d_out, int out_size, void* d_ws, size_t ws_size,
                              hipStream_t stream)
{
    const float* input   = (const float*)d_in[0];
    const int*   uu      = (const int*)  d_in[1];
    const int*   vv      = (const int*)  d_in[2];
    const float* valid   = (const float*)d_in[3];
    const float* density = (const float*)d_in[4];
    float*       out     = (float*)d_out;

    const size_t T_bytes = (size_t)PIX * C_IN * sizeof(__half);   // 26.3 MB
    if (ws_size >= T_bytes) {
        __half* T2 = (__half*)d_ws;
        transpose_f16_kernel<<<dim3(PIX / TA_P, C_IN / TA_C), dim3(256), 0, stream>>>(input, T2);
        gather_f16_kernel<<<dim3(LVOX / VB), dim3(256), 0, stream>>>(T2, uu, vv, valid, density, out);
    } else {
        voxel_proj_direct<<<dim3(LVOX / 256, C_IN / CPT), dim3(256), 0, stream>>>(
            input, uu, vv, valid, density, out);
    }
}

// Round 5
// 72.566 us; speedup vs baseline: 3.6543x; 1.2711x over previous
//
#include <hip/hip_runtime.h>
#include <hip/hip_fp16.h>

// VoxelProjection_fish — two-phase: (A) transpose input to pixel-major fp16 (padded rows),
// (B) contiguous per-voxel gather w/ register prefetch + LDS transpose + NT coalesced store.

#define C_IN  336
#define ZB    6
#define BEV_H 240
#define BEV_W 120
#define LVOX  (ZB * BEV_H * BEV_W)   // 172800
#define HF    160
#define WF    256
#define PIX   (HF * WF)              // 40960
#define HW    (BEV_H * BEV_W)        // 28800

// T2 layout: row per pixel, ROWH halves, 3 chunks of 112 ch at half-offsets 0/128/256
// (each chunk start 256B-aligned -> every 224B chunk read spans exactly 4 aligned 64B lines)
#define ROWH  384                    // halves per row (768 B)
#define CHH   128                    // half-offset stride between chunks

typedef float f32x4 __attribute__((ext_vector_type(4)));   // NT-store-compatible

// ---------- Kernel A: transpose input [C_IN][PIX] f32 -> T2 [PIX][ROWH] f16 ----------
#define TA_P 64
#define TA_C 48   // 336 = 7 * 48
__global__ __launch_bounds__(256) void transpose_f16_kernel(
    const float* __restrict__ in, __half* __restrict__ T2)
{
    __shared__ float tile[TA_C][TA_P + 1];
    const int p0 = blockIdx.x * TA_P;
    const int c0 = blockIdx.y * TA_C;
    const int t  = threadIdx.x;

    #pragma unroll
    for (int i = 0; i < (TA_P * TA_C) / 256; ++i) {   // 12
        int idx = i * 256 + t;
        int cl = idx >> 6;
        int pl = idx & 63;
        tile[cl][pl] = in[(size_t)(c0 + cl) * PIX + p0 + pl];   // coalesced 256B rows
    }
    __syncthreads();
    #pragma unroll
    for (int i = 0; i < (TA_P * TA_C / 2) / 256; ++i) {   // 6: one half2 per thread
        int idx = i * 256 + t;
        int cl2 = idx % (TA_C / 2);
        int pl  = idx / (TA_C / 2);
        int c   = c0 + 2 * cl2;                // even; pairs never straddle 112-boundaries
        int chunk = c / 112;
        int poff  = chunk * CHH + (c - chunk * 112);
        __half2 hv = __floats2half2_rn(tile[2 * cl2][pl], tile[2 * cl2 + 1][pl]);
        *reinterpret_cast<__half2*>(&T2[(size_t)(p0 + pl) * ROWH + poff]) = hv;
    }
}

// ---------- Kernel B: gather fp16 rows, weight, LDS transpose, NT store ----------
#define VB   64                // voxels per block (64 | 28800 -> z uniform)
#define CC   112               // channels per chunk (336 = 3 * 112)
#define NCH  (C_IN / CC)       // 3
#define LROW (VB + 1)          // 65 floats: phase-3 reads 2-way max (free)
#define NGPV (CC / 4)          // 28 uint2 granules per voxel-chunk
#define NG   ((VB * NGPV) / 256)  // 7 granules per thread

__global__ __launch_bounds__(256) void gather_f16_kernel(
    const __half* __restrict__ T2,
    const int*    __restrict__ uu,
    const int*    __restrict__ vv,
    const float*  __restrict__ valid,
    const float*  __restrict__ density,
    float*        __restrict__ out)
{
    __shared__ float tile[CC * LROW];   // 29.1 KB -> 5 blocks/CU
    __shared__ int   p_s[VB];
    __shared__ float w_s[VB];

    const int t   = threadIdx.x;
    const int l0  = blockIdx.x * VB;
    const int z   = l0 / HW;            // wave-uniform
    const int hw0 = l0 - z * HW;

    if (t < VB) {
        int l = l0 + t;
        p_s[t] = vv[l] * WF + uu[l];
        w_s[t] = valid[l] * density[l];
    }
    __syncthreads();

    // Per-thread fixed (voxel, granule) assignment; weights/pixels into regs.
    int   vi[NG], gi[NG], myp[NG];
    float myw[NG];
    #pragma unroll
    for (int i = 0; i < NG; ++i) {
        int idx = i * 256 + t;
        vi[i]  = idx / NGPV;
        gi[i]  = idx - vi[i] * NGPV;
        myp[i] = p_s[vi[i]];
        myw[i] = w_s[vi[i]];
    }

    // Prefetch chunk 0 into regs.
    uint2 pf[NG];
    #pragma unroll
    for (int i = 0; i < NG; ++i)
        pf[i] = *reinterpret_cast<const uint2*>(
            &T2[(size_t)myp[i] * ROWH + gi[i] * 4]);

    #pragma unroll
    for (int ch = 0; ch < NCH; ++ch) {
        // Unpack + weight -> LDS [c][v]
        #pragma unroll
        for (int i = 0; i < NG; ++i) {
            const float2 f01 = __half22float2(*reinterpret_cast<const __half2*>(&pf[i].x));
            const float2 f23 = __half22float2(*reinterpret_cast<const __half2*>(&pf[i].y));
            const float w = myw[i];
            int base = (gi[i] * 4) * LROW + vi[i];
            tile[base]          = f01.x * w;
            tile[base + LROW]   = f01.y * w;
            tile[base + 2*LROW] = f23.x * w;
            tile[base + 3*LROW] = f23.y * w;
        }
        __syncthreads();

        // T14: issue next chunk's gathers now; they stay in flight through the store phase.
        if (ch + 1 < NCH) {
            #pragma unroll
            for (int i = 0; i < NG; ++i)
                pf[i] = *reinterpret_cast<const uint2*>(
                    &T2[(size_t)myp[i] * ROWH + (ch + 1) * CHH + gi[i] * 4]);
        }

        // Store phase: per channel-row, 16 lanes x float4 = 256B coalesced NT stores.
        {
            const int vq = (t & 15) * 4;
            const int cb = t >> 4;
            #pragma unroll
            for (int i2 = 0; i2 < CC / 16; ++i2) {   // 7
                int cl = i2 * 16 + cb;
                f32x4 o;
                o.x = tile[cl * LROW + vq + 0];
                o.y = tile[cl * LROW + vq + 1];
                o.z = tile[cl * LROW + vq + 2];
                o.w = tile[cl * LROW + vq + 3];
                __builtin_nontemporal_store(o, reinterpret_cast<f32x4*>(
                    &out[(size_t)(z * C_IN + ch * CC + cl) * HW + hw0 + vq]));
            }
        }
        __syncthreads();
    }
}

// ---------- Fallback: direct scattered gather (round-1 kernel) ----------
#define CPT 16
__global__ __launch_bounds__(256) void voxel_proj_direct(
    const float* __restrict__ input,
    const int*   __restrict__ uu,
    const int*   __restrict__ vv,
    const float* __restrict__ valid,
    const float* __restrict__ density,
    float*       __restrict__ out)
{
    const int l = blockIdx.x * 256 + threadIdx.x;
    const int p = vv[l] * WF + uu[l];
    const float w = valid[l] * density[l];
    const int z  = l / HW;
    const int hw = l - z * HW;
    const float* inb  = input + p;
    float*       outb = out + (size_t)z * C_IN * HW + hw;
    const int c0 = blockIdx.y * CPT;
    #pragma unroll
    for (int i = 0; i < CPT; ++i) {
        const int c = c0 + i;
        outb[(size_t)c * HW] = inb[(size_t)c * PIX] * w;
    }
}

extern "C" void kernel_launch(void* const* d_in, const int* in_sizes, int n_in,
                              void* d_out, int out_size, void* d_ws, size_t ws_size,
                              hipStream_t stream)
{
    const float* input   = (const float*)d_in[0];
    const int*   uu      = (const int*)  d_in[1];
    const int*   vv      = (const int*)  d_in[2];
    const float* valid   = (const float*)d_in[3];
    const float* density = (const float*)d_in[4];
    float*       out     = (float*)d_out;

    const size_t T_bytes = (size_t)PIX * ROWH * sizeof(__half);   // 31.5 MB
    if (ws_size >= T_bytes) {
        __half* T2 = (__half*)d_ws;
        transpose_f16_kernel<<<dim3(PIX / TA_P, C_IN / TA_C), dim3(256), 0, stream>>>(input, T2);
        gather_f16_kernel<<<dim3(LVOX / VB), dim3(256), 0, stream>>>(T2, uu, vv, valid, density, out);
    } else {
        voxel_proj_direct<<<dim3(LVOX / 256, C_IN / CPT), dim3(256), 0, stream>>>(
            input, uu, vv, valid, density, out);
    }
}